// Round 6
// baseline (1229.954 us; speedup 1.0000x reference)
//
#include <hip/hip_runtime.h>
#include <hip/hip_fp16.h>

// GCN 2-layer: out = Ahat( relu( Ahat(x) W1 + b1 ) W2 ) + b2, Ahat = D^-1/2 (A+I) D^-1/2.
// N=100000, E=1.6M, dims 64->128->64.
//
// R13 (ILP) and R14 (TLP) both flat at ~60-62us for the gather => the memory
// system is saturated: FETCH 83.5MB vs 12.8MB payload buffer = 62% L2 hit rate;
// misses go to L3 at ~600-900cy and the per-CU miss queue drains at a fixed
// rate. The remaining lever is LOCALITY, not parallelism.
// R15: src-sorted streaming aggregation with LDS accumulators.
//  - k_finish counting-sorts each dst-bucket's edges by src>>9 (64KB windows);
//    CSR (row_ptr/col) dropped entirely.
//  - agg kernels: one block per bucket (256 blocks = 1/CU), accS[400][65] fp32
//    in LDS (104KB, stride-65 => bank = row+8k+j, ~2-way). Groups stream sorted
//    pairs, gather Y[src] (128B rows), ds_add_f32 into dst row. All blocks walk
//    src 0->100K in lockstep => each XCD's L2 holds the same small src window.
//  - k_agg_mlp: MFMA MLP on 16-row strips straight out of accS (per-wave Hs).
// Predicted: agg FETCH 83.5 -> ~25MB, agg_mlp 62 -> ~22us, agg_out ~20us,
// total 234 -> ~160us.

#define DIM 64
#define NB 256          // dst-range buckets
#define SPAN 391        // ceil(100000/256); NB*SPAN >= N; SPAN < 512
#define SPAN_PAD 400    // accS rows (covers strip tail reads to row 399)
#define AS 65           // accS row stride in floats (65%32==1 -> bank spread)
#define BK_TILE 4096
#define BK_PER 16       // edges per thread in k_bucket

typedef _Float16 f16x8 __attribute__((ext_vector_type(8)));
typedef float f32x4 __attribute__((ext_vector_type(4)));

__device__ __forceinline__ void atomAddF(float* p, float v) {
    unsafeAtomicAdd(p, v);
}

// 8 halves (packed in float4) -> add into 8 fp32 accumulators
__device__ __forceinline__ void h8_add(const float4 v, float* acc) {
    const __half2* hp = (const __half2*)&v;
    #pragma unroll
    for (int i = 0; i < 4; ++i) {
        float2 t = __half22float2(hp[i]);
        acc[2 * i] += t.x;
        acc[2 * i + 1] += t.y;
    }
}
// 8 fp32 -> 8 halves packed in a float4
__device__ __forceinline__ float4 f8_to_h8(const float* f) {
    __half2 hh[4];
    hh[0] = __float22half2_rn(make_float2(f[0], f[1]));
    hh[1] = __float22half2_rn(make_float2(f[2], f[3]));
    hh[2] = __float22half2_rn(make_float2(f[4], f[5]));
    hh[3] = __float22half2_rn(make_float2(f[6], f[7]));
    return *(float4*)hh;
}

// Accumulate one edge's 16B payload (8 halves, this lane's col chunk) into the
// LDS dst row via ds_add_f32. Bank = (row + 8*lane + i) % 32 with AS=65.
__device__ __forceinline__ void lds_acc_edge(float* accS, unsigned pr, float4 v, int lane) {
    float* rb = &accS[(pr & 511u) * AS + lane * 8];
    const __half2* hp = (const __half2*)&v;
    float2 t0 = __half22float2(hp[0]);
    float2 t1 = __half22float2(hp[1]);
    float2 t2 = __half22float2(hp[2]);
    float2 t3 = __half22float2(hp[3]);
    atomicAdd(rb + 0, t0.x); atomicAdd(rb + 1, t0.y);
    atomicAdd(rb + 2, t1.x); atomicAdd(rb + 3, t1.y);
    atomicAdd(rb + 4, t2.x); atomicAdd(rb + 5, t2.y);
    atomicAdd(rb + 6, t3.x); atomicAdd(rb + 7, t3.y);
}

// ---------------- weight prep (+ bcnt zeroing piggyback) ----------------
__global__ __launch_bounds__(256) void k_wconv(const float* __restrict__ W1,
                                               const float* __restrict__ W2,
                                               _Float16* __restrict__ W1t,
                                               _Float16* __restrict__ W2t,
                                               int* __restrict__ bcnt) {
    int idx = blockIdx.x * 256 + threadIdx.x;
    if (blockIdx.x == 0) bcnt[threadIdx.x] = 0;
    if (idx < 8192) {                       // W1t: [128 n][64 k]
        int n = idx >> 6, k = idx & 63;
        W1t[idx] = (_Float16)W1[k * 128 + n];
    } else if (idx < 16384) {               // W2t: [64 n][128 k]
        int j = idx - 8192;
        int n = j >> 7, k = j & 127;
        W2t[j] = (_Float16)W2[k * 64 + n];
    }
}

// ---------------- bucket totals ----------------
__global__ __launch_bounds__(256) void k_hist256(const int* __restrict__ ei,
                                                 int* __restrict__ bucketCnt, int E) {
    __shared__ int h[NB];
    const int tid = threadIdx.x;
    h[tid] = 0;
    __syncthreads();
    const int base = blockIdx.x * BK_TILE;
    #pragma unroll
    for (int j = 0; j < BK_TILE; j += 256) {
        int e = base + j + tid;
        if (e < E) atomicAdd(&h[(unsigned)ei[E + e] / (unsigned)SPAN], 1);
    }
    __syncthreads();
    if (h[tid]) atomicAdd(&bucketCnt[tid], h[tid]);
}
__global__ __launch_bounds__(256) void k_scan_b(const int* __restrict__ bucketCnt,
                                                int* __restrict__ bucketBase,
                                                int* __restrict__ gcur) {
    __shared__ int s[NB];
    const int tid = threadIdx.x;
    int v = bucketCnt[tid];
    s[tid] = v;
    __syncthreads();
    for (int off = 1; off < NB; off <<= 1) {
        int t = (tid >= off) ? s[tid - off] : 0;
        __syncthreads();
        s[tid] += t;
        __syncthreads();
    }
    int ex = s[tid] - v;
    bucketBase[tid] = ex;
    gcur[tid] = ex;
    if (tid == NB - 1) bucketBase[NB] = s[NB - 1];
}

// Phase A: tile multisplit -> bucket-grouped packed edges ((src<<9)|local_dst).
__global__ __launch_bounds__(256) void k_bucket(const int* __restrict__ ei,
                                                int* __restrict__ gcur,
                                                unsigned* __restrict__ pairs, int E) {
    __shared__ int scn[NB];
    __shared__ int run[NB];
    __shared__ int lbase[NB];
    __shared__ int gbase[NB];
    __shared__ unsigned stage[BK_TILE];
    __shared__ unsigned char bkt[BK_TILE];
    const int tid = threadIdx.x;
    const int base = blockIdx.x * BK_TILE;

    scn[tid] = 0;
    __syncthreads();

    unsigned pv[BK_PER];
    int bv[BK_PER];
    #pragma unroll
    for (int j = 0; j < BK_PER; ++j) {
        int e = base + j * 256 + tid;
        if (e < E) {
            unsigned s = (unsigned)ei[e];
            unsigned d = (unsigned)ei[E + e];
            int b = (int)(d / (unsigned)SPAN);
            bv[j] = b;
            pv[j] = (s << 9) | (d - (unsigned)b * SPAN);
            atomicAdd(&scn[b], 1);
        } else bv[j] = -1;
    }
    __syncthreads();
    int c = scn[tid];
    for (int off = 1; off < 256; off <<= 1) {
        int t = (tid >= off) ? scn[tid - off] : 0;
        __syncthreads();
        scn[tid] += t;
        __syncthreads();
    }
    int ex = scn[tid] - c;
    lbase[tid] = ex;
    run[tid] = ex;
    if (c > 0) gbase[tid] = atomicAdd(&gcur[tid], c);
    __syncthreads();

    #pragma unroll
    for (int j = 0; j < BK_PER; ++j) {
        if (bv[j] >= 0) {
            int p = atomicAdd(&run[bv[j]], 1);
            stage[p] = pv[j];
            bkt[p] = (unsigned char)bv[j];
        }
    }
    __syncthreads();

    int total = min(BK_TILE, E - base);
    for (int i = tid; i < total; i += 256) {
        int bb = bkt[i];
        pairs[gbase[bb] + (i - lbase[bb])] = stage[i];
    }
}

// Phase B: one block per bucket. dst hist -> dinv + prescale Y, and counting
// sort of the bucket's pairs by src>>9 into pairs2 (64KB src windows).
__global__ __launch_bounds__(256) void k_finish(const unsigned* __restrict__ pairs,
                                                const int* __restrict__ bucketBase,
                                                float* __restrict__ dinv,
                                                unsigned* __restrict__ pairs2,
                                                const float* __restrict__ x,
                                                __half* __restrict__ Y, int N) {
    __shared__ int lh[512];
    __shared__ int sh[256];
    __shared__ int scn[256];
    const int tid = threadIdx.x;
    const int b = blockIdx.x;
    const int lo = b * SPAN;
    const int hi = min(lo + SPAN, N);
    const int nn = hi - lo;
    const int p0 = bucketBase[b];
    const int p1 = bucketBase[b + 1];

    for (int i = tid; i < 512; i += 256) lh[i] = 0;
    sh[tid] = 0;
    __syncthreads();
    for (int e = p0 + tid; e < p1; e += 256) {
        unsigned pr = pairs[e];
        atomicAdd(&lh[pr & 511u], 1);
        atomicAdd(&sh[pr >> 18], 1);       // src>>9 bin (src<2^17 -> bin<196)
    }
    __syncthreads();
    int v = sh[tid];
    scn[tid] = v;
    __syncthreads();
    for (int off = 1; off < 256; off <<= 1) {
        int t = (tid >= off) ? scn[tid - off] : 0;
        __syncthreads();
        scn[tid] += t;
        __syncthreads();
    }
    sh[tid] = p0 + scn[tid] - v;           // exclusive base -> running cursor
    __syncthreads();
    for (int e = p0 + tid; e < p1; e += 256) {
        unsigned pr = pairs[e];
        int pos = atomicAdd(&sh[pr >> 18], 1);
        pairs2[pos] = pr;
    }
    // dinv + fused prescale: Y[row] = half(dinv[row] * x[row])
    for (int i = tid; i < nn; i += 256)
        dinv[lo + i] = rsqrtf(1.0f + (float)lh[i]);
    const int seg = tid & 7;
    for (int rr = tid >> 3; rr < nn; rr += 32) {
        float di = rsqrtf(1.0f + (float)lh[rr]);
        long row = lo + rr;
        float4 a = ((const float4*)x)[row * 16 + seg * 2];
        float4 c = ((const float4*)x)[row * 16 + seg * 2 + 1];
        float f[8] = {a.x * di, a.y * di, a.z * di, a.w * di,
                      c.x * di, c.y * di, c.z * di, c.w * di};
        ((float4*)Y)[row * 8 + seg] = f8_to_h8(f);
    }
}

// Streaming accumulate: 64 groups x 8 lanes, each group takes 8 consecutive
// src-sorted edges per iteration (stride 512). Gather payload row, ds_add into
// the LDS dst row.
__device__ __forceinline__ void stream_acc(float* accS,
                                           const unsigned* __restrict__ pairs2,
                                           const float4* __restrict__ P4,
                                           int p0, int p1, int grp, int lane) {
    for (int e8 = p0 + grp * 8; e8 < p1; e8 += 512) {
        const int cnt = min(8, p1 - e8);
        if (cnt == 8) {
            unsigned pr0 = pairs2[e8 + 0], pr1 = pairs2[e8 + 1];
            unsigned pr2 = pairs2[e8 + 2], pr3 = pairs2[e8 + 3];
            unsigned pr4 = pairs2[e8 + 4], pr5 = pairs2[e8 + 5];
            unsigned pr6 = pairs2[e8 + 6], pr7 = pairs2[e8 + 7];
            float4 v0 = P4[(long)(pr0 >> 9) * 8 + lane];
            float4 v1 = P4[(long)(pr1 >> 9) * 8 + lane];
            float4 v2 = P4[(long)(pr2 >> 9) * 8 + lane];
            float4 v3 = P4[(long)(pr3 >> 9) * 8 + lane];
            float4 v4 = P4[(long)(pr4 >> 9) * 8 + lane];
            float4 v5 = P4[(long)(pr5 >> 9) * 8 + lane];
            float4 v6 = P4[(long)(pr6 >> 9) * 8 + lane];
            float4 v7 = P4[(long)(pr7 >> 9) * 8 + lane];
            lds_acc_edge(accS, pr0, v0, lane);
            lds_acc_edge(accS, pr1, v1, lane);
            lds_acc_edge(accS, pr2, v2, lane);
            lds_acc_edge(accS, pr3, v3, lane);
            lds_acc_edge(accS, pr4, v4, lane);
            lds_acc_edge(accS, pr5, v5, lane);
            lds_acc_edge(accS, pr6, v6, lane);
            lds_acc_edge(accS, pr7, v7, lane);
        } else {
            for (int j = 0; j < cnt; ++j) {
                unsigned pr = pairs2[e8 + j];
                float4 v = P4[(long)(pr >> 9) * 8 + lane];
                lds_acc_edge(accS, pr, v, lane);
            }
        }
    }
}

// ---------------- agg1 + MFMA MLP: one block per bucket ----------------
// accS[r] = sum Y[src] over edges with dst = lo+r (fp32, LDS).
// Then per 16-row strip (per-wave private): A = half((accS+Y_self)*dinv),
// H = relu(A W1 + b1), X = half(dinv * H W2).  LDS 104.0 + 34.8 = 138.8 KB.
__global__ __launch_bounds__(512) void k_agg_mlp(const unsigned* __restrict__ pairs2,
                                                 const int* __restrict__ bucketBase,
                                                 const float* __restrict__ dinv,
                                                 const __half* __restrict__ Y,
                                                 const _Float16* __restrict__ W1t, // [128,64]
                                                 const float* __restrict__ b1,     // [128]
                                                 const _Float16* __restrict__ W2t, // [64,128]
                                                 _Float16* __restrict__ X,         // [N,64]
                                                 int N) {
    __shared__ float accS[SPAN_PAD * AS];            // 104,000 B
    __shared__ __align__(16) _Float16 Hs[8 * 16 * 136]; // 34,816 B (per-wave strips)
    const int tid = threadIdx.x;
    const int b = blockIdx.x;
    const int lo = b * SPAN;
    const int nn = min(SPAN, N - lo);
    const int p0 = bucketBase[b];
    const int p1 = bucketBase[b + 1];

    for (int i = tid; i < SPAN_PAD * AS; i += 512) accS[i] = 0.f;
    __syncthreads();

    const int grp = tid >> 3;
    const int lane = tid & 7;
    const float4* Y4 = (const float4*)Y;
    stream_acc(accS, pairs2, Y4, p0, p1, grp, lane);
    __syncthreads();

    // ---- MLP strips: wave wv owns strips wv, wv+8, ... (no barriers inside) ----
    const int wv = tid >> 6;
    const int l64 = tid & 63;
    const int lr = l64 & 15;
    const int lg = l64 >> 4;
    _Float16* HsW = &Hs[wv * (16 * 136)];
    const _Float16* wb1 = W1t + lr * 64 + lg * 8;
    const _Float16* wb2 = W2t + lr * 128 + lg * 8;
    const int nStrips = (nn + 15) >> 4;
    for (int s = wv; s < nStrips; s += 8) {
        const int r0 = s * 16;
        const int ra = r0 + lr;              // A row (local); < SPAN_PAD always
        const int ga = lo + ra;
        float di = (ra < nn) ? dinv[ga] : 0.f;
        float4 ya = make_float4(0.f, 0.f, 0.f, 0.f), yb = ya;
        if (ra < nn) {
            ya = Y4[(long)ga * 8 + lg];          // cols [lg*8, lg*8+8)
            yb = Y4[(long)ga * 8 + 4 + lg];      // cols [32+lg*8, +8)
        }
        float fa[8] = {}, fb[8] = {};
        h8_add(ya, fa);
        h8_add(yb, fb);
        const float* ar = &accS[ra * AS];
        f16x8 a0, a1;
        #pragma unroll
        for (int i = 0; i < 8; ++i) {
            a0[i] = (_Float16)((ar[lg * 8 + i] + fa[i]) * di);
            a1[i] = (_Float16)((ar[32 + lg * 8 + i] + fb[i]) * di);
        }
        f32x4 acc[8];
        #pragma unroll
        for (int nt = 0; nt < 8; ++nt) acc[nt] = (f32x4){0.f, 0.f, 0.f, 0.f};
        #pragma unroll
        for (int nt = 0; nt < 8; ++nt) {
            f16x8 b0 = *(const f16x8*)(wb1 + nt * 1024);
            f16x8 bK = *(const f16x8*)(wb1 + nt * 1024 + 32);
            acc[nt] = __builtin_amdgcn_mfma_f32_16x16x32_f16(a0, b0, acc[nt], 0, 0, 0);
            acc[nt] = __builtin_amdgcn_mfma_f32_16x16x32_f16(a1, bK, acc[nt], 0, 0, 0);
        }
        #pragma unroll
        for (int nt = 0; nt < 8; ++nt) {
            float bv = b1[nt * 16 + lr];
            #pragma unroll
            for (int r = 0; r < 4; ++r) {
                float h = fmaxf(acc[nt][r] + bv, 0.f);
                HsW[(lg * 4 + r) * 136 + nt * 16 + lr] = (_Float16)h;
            }
        }
        asm volatile("s_waitcnt lgkmcnt(0)" ::: "memory");
        const _Float16* hrow = &HsW[lr * 136 + lg * 8];
        f32x4 acc2[4];
        #pragma unroll
        for (int nt = 0; nt < 4; ++nt) acc2[nt] = (f32x4){0.f, 0.f, 0.f, 0.f};
        #pragma unroll
        for (int kk = 0; kk < 4; ++kk) {
            f16x8 a = *(const f16x8*)(hrow + kk * 32);
            #pragma unroll
            for (int nt = 0; nt < 4; ++nt) {
                f16x8 bb = *(const f16x8*)(wb2 + nt * 2048 + kk * 32);
                acc2[nt] = __builtin_amdgcn_mfma_f32_16x16x32_f16(a, bb, acc2[nt], 0, 0, 0);
            }
        }
        float sc4[4];
        #pragma unroll
        for (int r = 0; r < 4; ++r) {
            int rl = r0 + lg * 4 + r;
            sc4[r] = (rl < nn) ? dinv[lo + rl] : 0.f;
        }
        asm volatile("s_waitcnt lgkmcnt(0)" ::: "memory");
        _Float16* Os = HsW;                  // reuse as [16][72] halves
        #pragma unroll
        for (int nt = 0; nt < 4; ++nt) {
            #pragma unroll
            for (int r = 0; r < 4; ++r)
                Os[(lg * 4 + r) * 72 + nt * 16 + lr] = (_Float16)(acc2[nt][r] * sc4[r]);
        }
        asm volatile("s_waitcnt lgkmcnt(0)" ::: "memory");
        {
            int rr = l64 >> 2, c0 = (l64 & 3) * 16;
            int rl = r0 + rr;
            if (rl < nn) {
                f16x8 w0 = *(const f16x8*)&Os[rr * 72 + c0];
                f16x8 w1 = *(const f16x8*)&Os[rr * 72 + c0 + 8];
                *(f16x8*)(X + (long)(lo + rl) * 64 + c0) = w0;
                *(f16x8*)(X + (long)(lo + rl) * 64 + c0 + 8) = w1;
            }
        }
    }
}

// ---------------- agg2: one block per bucket; out = dinv*(X_self+acc) + b2 ----
__global__ __launch_bounds__(512) void k_agg_out(const unsigned* __restrict__ pairs2,
                                                 const int* __restrict__ bucketBase,
                                                 const float* __restrict__ dinv,
                                                 const __half* __restrict__ Xh,
                                                 const float* __restrict__ bias,
                                                 float* __restrict__ out, int N) {
    __shared__ float accS[SPAN_PAD * AS];            // 104,000 B
    const int tid = threadIdx.x;
    const int b = blockIdx.x;
    const int lo = b * SPAN;
    const int nn = min(SPAN, N - lo);
    const int p0 = bucketBase[b];
    const int p1 = bucketBase[b + 1];

    for (int i = tid; i < SPAN_PAD * AS; i += 512) accS[i] = 0.f;
    __syncthreads();

    const int grp = tid >> 3;
    const int lane = tid & 7;
    const float4* X4 = (const float4*)Xh;
    stream_acc(accS, pairs2, X4, p0, p1, grp, lane);
    __syncthreads();

    float4 bb0 = ((const float4*)bias)[lane * 2];
    float4 bb1 = ((const float4*)bias)[lane * 2 + 1];
    for (int r = grp; r < nn; r += 64) {
        int g = lo + r;
        float4 xv = X4[(long)g * 8 + lane];
        float f[8] = {};
        h8_add(xv, f);
        const float* rb = &accS[r * AS + lane * 8];
        float di = dinv[g];
        float res[8];
        #pragma unroll
        for (int i = 0; i < 8; ++i) res[i] = (rb[i] + f[i]) * di;
        res[0] += bb0.x; res[1] += bb0.y; res[2] += bb0.z; res[3] += bb0.w;
        res[4] += bb1.x; res[5] += bb1.y; res[6] += bb1.z; res[7] += bb1.w;
        *(float4*)&out[(long)g * 64 + lane * 8]     = make_float4(res[0], res[1], res[2], res[3]);
        *(float4*)&out[(long)g * 64 + lane * 8 + 4] = make_float4(res[4], res[5], res[6], res[7]);
    }
}

// ---------------- fallback path (float, atomic scatter; only if ws too small) ----------------
__global__ __launch_bounds__(256) void k_init_deg(float* deg, int n) {
    int i = blockIdx.x * 256 + threadIdx.x;
    if (i < n) deg[i] = 1.0f;
}
__global__ __launch_bounds__(256) void k_count_deg(const int* __restrict__ ei, float* deg, int E) {
    int e = blockIdx.x * 256 + threadIdx.x;
    if (e < E) atomAddF(&deg[ei[E + e]], 1.0f);
}
__global__ __launch_bounds__(256) void k_rsqrt(float* deg, int n) {
    int i = blockIdx.x * 256 + threadIdx.x;
    if (i < n) deg[i] = rsqrtf(deg[i]);
}
template<bool BIAS>
__global__ __launch_bounds__(256) void k_self(const float* __restrict__ src,
                                              const float* __restrict__ dinv,
                                              const float* __restrict__ b,
                                              float* __restrict__ out, int n) {
    int g = blockIdx.x * 256 + threadIdx.x;
    int i = g >> 4, c = g & 15;
    if (i >= n) return;
    float di = dinv[i];
    float s = di * di;
    float4 v = *(const float4*)&src[(long)i * DIM + c * 4];
    float4 r = make_float4(v.x * s, v.y * s, v.z * s, v.w * s);
    if (BIAS) {
        float4 bv = *(const float4*)&b[c * 4];
        r.x += bv.x; r.y += bv.y; r.z += bv.z; r.w += bv.w;
    }
    *(float4*)&out[(long)i * DIM + c * 4] = r;
}
__global__ __launch_bounds__(256) void k_edge_agg(const int* __restrict__ ei,
                                                  const float* __restrict__ dinv,
                                                  const float* __restrict__ h,
                                                  float* __restrict__ out, int E) {
    int t = threadIdx.x;
    int e = blockIdx.x * 16 + (t >> 4);
    if (e >= E) return;
    int lane = t & 15;
    int s = ei[e];
    int d = ei[E + e];
    float norm = dinv[s] * dinv[d];
    float4 hv = *(const float4*)&h[(long)s * DIM + lane * 4];
    float* o = &out[(long)d * DIM + lane * 4];
    atomAddF(o + 0, hv.x * norm);
    atomAddF(o + 1, hv.y * norm);
    atomAddF(o + 2, hv.z * norm);
    atomAddF(o + 3, hv.w * norm);
}
// float-I/O MLP for the fallback path
__global__ __launch_bounds__(256) void k_mlp_f(const float* __restrict__ G,
                                               const float* __restrict__ W1,
                                               const float* __restrict__ b1,
                                               const float* __restrict__ W2,
                                               float* __restrict__ T, int M) {
    __shared__ float Ws[64 * 128];
    __shared__ float HA[64 * 132];
    const int tid = threadIdx.x;
    const int row0 = blockIdx.x * 64;
    const int ty = tid >> 4;
    const int tx = tid & 15;
    #pragma unroll
    for (int l = 0; l < 4; ++l) {
        int idx = l * 256 + tid;
        int r = idx >> 4, cv = idx & 15;
        int gr = row0 + r;
        float4 v = make_float4(0.f, 0.f, 0.f, 0.f);
        if (gr < M) v = *(const float4*)&G[(long)gr * DIM + cv * 4];
        *(float4*)&HA[r * 68 + cv * 4] = v;
    }
    #pragma unroll
    for (int l = 0; l < 8; ++l) {
        int idx = (l * 256 + tid) * 4;
        *(float4*)&Ws[idx] = *(const float4*)&W1[idx];
    }
    __syncthreads();
    float4 accA[4], accB[4];
    #pragma unroll
    for (int i = 0; i < 4; ++i) {
        accA[i] = make_float4(0.f, 0.f, 0.f, 0.f);
        accB[i] = make_float4(0.f, 0.f, 0.f, 0.f);
    }
    for (int k4 = 0; k4 < 64; k4 += 4) {
        float4 a[4];
        #pragma unroll
        for (int i = 0; i < 4; ++i) a[i] = *(const float4*)&HA[(ty * 4 + i) * 68 + k4];
        #pragma unroll
        for (int kk = 0; kk < 4; ++kk) {
            const float* wr = &Ws[(k4 + kk) * 128 + tx * 8];
            float4 wA = *(const float4*)wr;
            float4 wB = *(const float4*)(wr + 4);
            #pragma unroll
            for (int i = 0; i < 4; ++i) {
                float ak = (&a[i].x)[kk];
                accA[i].x += ak * wA.x; accA[i].y += ak * wA.y;
                accA[i].z += ak * wA.z; accA[i].w += ak * wA.w;
                accB[i].x += ak * wB.x; accB[i].y += ak * wB.y;
                accB[i].z += ak * wB.z; accB[i].w += ak * wB.w;
            }
        }
    }
    __syncthreads();
    {
        float4 bA = *(const float4*)&b1[tx * 8];
        float4 bB = *(const float4*)&b1[tx * 8 + 4];
        #pragma unroll
        for (int i = 0; i < 4; ++i) {
            float4 hA = make_float4(fmaxf(accA[i].x + bA.x, 0.f), fmaxf(accA[i].y + bA.y, 0.f),
                                    fmaxf(accA[i].z + bA.z, 0.f), fmaxf(accA[i].w + bA.w, 0.f));
            float4 hB = make_float4(fmaxf(accB[i].x + bB.x, 0.f), fmaxf(accB[i].y + bB.y, 0.f),
                                    fmaxf(accB[i].z + bB.z, 0.f), fmaxf(accB[i].w + bB.w, 0.f));
            *(float4*)&HA[(ty * 4 + i) * 132 + tx * 8 + 0] = hA;
            *(float4*)&HA[(ty * 4 + i) * 132 + tx * 8 + 4] = hB;
        }
    }
    #pragma unroll
    for (int l = 0; l < 8; ++l) {
        int idx = (l * 256 + tid) * 4;
        *(float4*)&Ws[idx] = *(const float4*)&W2[idx];
    }
    __syncthreads();
    float4 o[4];
    #pragma unroll
    for (int i = 0; i < 4; ++i) o[i] = make_float4(0.f, 0.f, 0.f, 0.f);
    for (int k4 = 0; k4 < 128; k4 += 4) {
        float4 a[4];
        #pragma unroll
        for (int i = 0; i < 4; ++i) a[i] = *(const float4*)&HA[(ty * 4 + i) * 132 + k4];
        #pragma unroll
        for (int kk = 0; kk < 4; ++kk) {
            float4 w = *(const float4*)&Ws[(k4 + kk) * 64 + tx * 4];
            #pragma unroll
            for (int i = 0; i < 4; ++i) {
                float ak = (&a[i].x)[kk];
                o[i].x += ak * w.x; o[i].y += ak * w.y;
                o[i].z += ak * w.z; o[i].w += ak * w.w;
            }
        }
    }
    #pragma unroll
    for (int i = 0; i < 4; ++i) {
        int gr = row0 + ty * 4 + i;
        if (gr < M) *(float4*)&T[(long)gr * DIM + tx * 4] = o[i];
    }
}

extern "C" void kernel_launch(void* const* d_in, const int* in_sizes, int n_in,
                              void* d_out, int out_size, void* d_ws, size_t ws_size,
                              hipStream_t stream) {
    const float* x  = (const float*)d_in[0];
    const int*   ei = (const int*)d_in[1];   // [2,E] int32
    const float* W1 = (const float*)d_in[2];
    const float* b1 = (const float*)d_in[3];
    const float* W2 = (const float*)d_in[4];
    const float* b2 = (const float*)d_in[5];
    float* out = (float*)d_out;

    const int N = in_sizes[0] / DIM;   // 100000
    const int E = in_sizes[1] / 2;     // 1600000

    const int gn   = (N + 255) / 256;
    const int ge   = (E + 255) / 256;
    const int gmlp = (N + 63) / 64;
    const int gbk  = (E + BK_TILE - 1) / BK_TILE;

    // ws layout (256B-aligned bump).
    size_t off = 0;
    auto bump = [&](size_t bytes) { size_t o = off; off = (off + bytes + 255) & ~(size_t)255; return o; };
    size_t o_dinv   = bump((size_t)N * 4);
    size_t o_bcnt   = bump(NB * 4);
    size_t o_bbase  = bump((NB + 1) * 4);
    size_t o_gcur   = bump(NB * 4);
    size_t o_pairs  = bump((size_t)E * 4);         // dst-bucketed packed edges
    size_t o_pairs2 = bump((size_t)E * 4);         // src-sorted within bucket
    size_t o_X      = bump((size_t)N * DIM * 2);   // half MLP out (agg2 payload)
    size_t o_Y      = bump((size_t)N * DIM * 2);   // half prescaled x (agg1 payload)
    size_t o_W1t    = bump(128 * 64 * 2);          // half W1^T
    size_t o_W2t    = bump(64 * 128 * 2);          // half W2^T
    size_t need_csr = off;                         // ~38.8 MB

    char* ws = (char*)d_ws;

    if (ws_size >= need_csr) {
        float*    dinv   = (float*)(ws + o_dinv);
        int*      bcnt   = (int*)(ws + o_bcnt);
        int*      bbase  = (int*)(ws + o_bbase);
        int*      gcur   = (int*)(ws + o_gcur);
        unsigned* pairs  = (unsigned*)(ws + o_pairs);
        unsigned* pairs2 = (unsigned*)(ws + o_pairs2);
        __half*   X      = (__half*)(ws + o_X);
        __half*   Y      = (__half*)(ws + o_Y);
        _Float16* W1t    = (_Float16*)(ws + o_W1t);
        _Float16* W2t    = (_Float16*)(ws + o_W2t);

        k_wconv<<<64, 256, 0, stream>>>(W1, W2, W1t, W2t, bcnt);
        k_hist256<<<gbk, 256, 0, stream>>>(ei, bcnt, E);
        k_scan_b<<<1, 256, 0, stream>>>(bcnt, bbase, gcur);
        k_bucket<<<gbk, 256, 0, stream>>>(ei, gcur, pairs, E);
        // dinv + prescale Y + src-sort pairs -> pairs2
        k_finish<<<NB, 256, 0, stream>>>(pairs, bbase, dinv, pairs2, x, Y, N);
        // X = half( dinv * relu( (Ahat x) W1 + b1 ) W2 )  (LDS-accum + MFMA MLP)
        k_agg_mlp<<<NB, 512, 0, stream>>>(pairs2, bbase, dinv, Y, W1t, b1, W2t,
                                          (_Float16*)X, N);
        // out = dinv[d]*(X[d] + sum X[s]) + b2   (LDS-accum + bias epilogue)
        k_agg_out<<<NB, 512, 0, stream>>>(pairs2, bbase, dinv, X, b2, out, N);
    } else {
        // -------- fallback (float atomic scatter) --------
        float* dinv = (float*)ws;
        float* buf  = (float*)(ws + 512 * 1024);
        int grow16 = ((long)N * 16 + 255) / 256;
        int gedge = (E + 15) / 16;

        k_init_deg<<<gn, 256, 0, stream>>>(dinv, N);
        k_count_deg<<<ge, 256, 0, stream>>>(ei, dinv, E);
        k_rsqrt<<<gn, 256, 0, stream>>>(dinv, N);

        k_self<false><<<grow16, 256, 0, stream>>>(x, dinv, nullptr, buf, N);
        k_edge_agg<<<gedge, 256, 0, stream>>>(ei, dinv, x, buf, E);
        k_mlp_f<<<gmlp, 256, 0, stream>>>(buf, W1, b1, W2, buf, N);
        k_self<true><<<grow16, 256, 0, stream>>>(buf, dinv, b2, out, N);
        k_edge_agg<<<gedge, 256, 0, stream>>>(ei, dinv, buf, out, E);
    }
}

// Round 7
// 310.925 us; speedup vs baseline: 3.9558x; 3.9558x over previous
//
#include <hip/hip_runtime.h>
#include <hip/hip_fp16.h>

// GCN 2-layer: out = Ahat( relu( Ahat(x) W1 + b1 ) W2 ) + b2, Ahat = D^-1/2 (A+I) D^-1/2.
// N=100000, E=1.6M, dims 64->128->64.
//
// R15 post-mortem: LDS-accumulator scatter was catastrophic (558us, all pipes
// idle): ~109M per-element LDS atomics through a generic float* (flat-atomic
// path) at 1 block/CU. Structure dead. What survives: the gather is L2-CAPACITY
// bound (Y 12.8MB vs 4MB/XCD L2 -> 62% hit; miss queue is the fixed-rate drain
// that nulled R13-ILP and R14-TLP).
// R16: column-chunked gather. Payload = 4 slabs [N][16]h = 3.2MB/slab < 4MB L2.
// Each agg = 4 dispatches, one slab each: all gathers hit a resident slab.
// Gather shape = proven R12 CSR walk, 8-deep window, 2 lanes/node x 16B.
// Same total loads/edge (8); latency class drops L3->L2. CSR build returns;
// standalone MFMA MLP (R11-proven) bridges full-row -> chunked.
// Predicted: agg 60 -> ~28us each, total 234.5 -> ~175us.

#define DIM 64
#define NB 256          // dst-range buckets
#define SPAN 391        // ceil(100000/256); NB*SPAN >= N; SPAN < 512
#define BK_TILE 4096
#define BK_PER 16       // edges per thread in k_bucket

typedef _Float16 f16x8 __attribute__((ext_vector_type(8)));
typedef float f32x4 __attribute__((ext_vector_type(4)));

__device__ __forceinline__ void atomAddF(float* p, float v) {
    unsafeAtomicAdd(p, v);
}

// 8 halves (packed in float4) -> add into 8 fp32 accumulators
__device__ __forceinline__ void h8_add(const float4 v, float* acc) {
    const __half2* hp = (const __half2*)&v;
    #pragma unroll
    for (int i = 0; i < 4; ++i) {
        float2 t = __half22float2(hp[i]);
        acc[2 * i] += t.x;
        acc[2 * i + 1] += t.y;
    }
}
// 8 fp32 -> 8 halves packed in a float4
__device__ __forceinline__ float4 f8_to_h8(const float* f) {
    __half2 hh[4];
    hh[0] = __float22half2_rn(make_float2(f[0], f[1]));
    hh[1] = __float22half2_rn(make_float2(f[2], f[3]));
    hh[2] = __float22half2_rn(make_float2(f[4], f[5]));
    hh[3] = __float22half2_rn(make_float2(f[6], f[7]));
    return *(float4*)hh;
}

// Chunked CSR gather: one 16-col slab, 2 lanes/node (p = half of the 32B row),
// 8-deep load window (R12-proven depth). P2 = slab as float4[], index node*2+p.
__device__ __forceinline__ void gatherc(const float4* __restrict__ P2,
                                        const int* __restrict__ col,
                                        int e, int e1, int p, float* accA, float* accB) {
    for (; e + 8 <= e1; e += 8) {
        int s0 = col[e], s1 = col[e + 1], s2 = col[e + 2], s3 = col[e + 3];
        int s4 = col[e + 4], s5 = col[e + 5], s6 = col[e + 6], s7 = col[e + 7];
        float4 v0 = P2[(long)s0 * 2 + p];
        float4 v1 = P2[(long)s1 * 2 + p];
        float4 v2 = P2[(long)s2 * 2 + p];
        float4 v3 = P2[(long)s3 * 2 + p];
        float4 v4 = P2[(long)s4 * 2 + p];
        float4 v5 = P2[(long)s5 * 2 + p];
        float4 v6 = P2[(long)s6 * 2 + p];
        float4 v7 = P2[(long)s7 * 2 + p];
        h8_add(v0, accA); h8_add(v1, accB);
        h8_add(v2, accA); h8_add(v3, accB);
        h8_add(v4, accA); h8_add(v5, accB);
        h8_add(v6, accA); h8_add(v7, accB);
    }
    for (; e + 2 <= e1; e += 2) {
        float4 v0 = P2[(long)col[e] * 2 + p];
        float4 v1 = P2[(long)col[e + 1] * 2 + p];
        h8_add(v0, accA); h8_add(v1, accB);
    }
    if (e < e1) h8_add(P2[(long)col[e] * 2 + p], accA);
}

// ---------------- weight prep (+ bcnt zeroing piggyback) ----------------
// W1t[n][k] = half(W1[k][n]), W2t[n][k] = half(W2[k][n]): a lane's 8 contiguous
// k-elements of the B fragment are one 16B load.
__global__ __launch_bounds__(256) void k_wconv(const float* __restrict__ W1,
                                               const float* __restrict__ W2,
                                               _Float16* __restrict__ W1t,
                                               _Float16* __restrict__ W2t,
                                               int* __restrict__ bcnt) {
    int idx = blockIdx.x * 256 + threadIdx.x;
    if (blockIdx.x == 0) bcnt[threadIdx.x] = 0;
    if (idx < 8192) {                       // W1t: [128 n][64 k]
        int n = idx >> 6, k = idx & 63;
        W1t[idx] = (_Float16)W1[k * 128 + n];
    } else if (idx < 16384) {               // W2t: [64 n][128 k]
        int j = idx - 8192;
        int n = j >> 7, k = j & 127;
        W2t[j] = (_Float16)W2[k * 64 + n];
    }
}

// ---------------- bucket totals ----------------
__global__ __launch_bounds__(256) void k_hist256(const int* __restrict__ ei,
                                                 int* __restrict__ bucketCnt, int E) {
    __shared__ int h[NB];
    const int tid = threadIdx.x;
    h[tid] = 0;
    __syncthreads();
    const int base = blockIdx.x * BK_TILE;
    #pragma unroll
    for (int j = 0; j < BK_TILE; j += 256) {
        int e = base + j + tid;
        if (e < E) atomicAdd(&h[(unsigned)ei[E + e] / (unsigned)SPAN], 1);
    }
    __syncthreads();
    if (h[tid]) atomicAdd(&bucketCnt[tid], h[tid]);
}
__global__ __launch_bounds__(256) void k_scan_b(const int* __restrict__ bucketCnt,
                                                int* __restrict__ bucketBase,
                                                int* __restrict__ gcur) {
    __shared__ int s[NB];
    const int tid = threadIdx.x;
    int v = bucketCnt[tid];
    s[tid] = v;
    __syncthreads();
    for (int off = 1; off < NB; off <<= 1) {
        int t = (tid >= off) ? s[tid - off] : 0;
        __syncthreads();
        s[tid] += t;
        __syncthreads();
    }
    int ex = s[tid] - v;
    bucketBase[tid] = ex;
    gcur[tid] = ex;
    if (tid == NB - 1) bucketBase[NB] = s[NB - 1];
}

// Phase A: tile multisplit -> bucket-grouped packed edges ((src<<9)|local_dst).
__global__ __launch_bounds__(256) void k_bucket(const int* __restrict__ ei,
                                                int* __restrict__ gcur,
                                                unsigned* __restrict__ pairs, int E) {
    __shared__ int scn[NB];
    __shared__ int run[NB];
    __shared__ int lbase[NB];
    __shared__ int gbase[NB];
    __shared__ unsigned stage[BK_TILE];
    __shared__ unsigned char bkt[BK_TILE];
    const int tid = threadIdx.x;
    const int base = blockIdx.x * BK_TILE;

    scn[tid] = 0;
    __syncthreads();

    unsigned pv[BK_PER];
    int bv[BK_PER];
    #pragma unroll
    for (int j = 0; j < BK_PER; ++j) {
        int e = base + j * 256 + tid;
        if (e < E) {
            unsigned s = (unsigned)ei[e];
            unsigned d = (unsigned)ei[E + e];
            int b = (int)(d / (unsigned)SPAN);
            bv[j] = b;
            pv[j] = (s << 9) | (d - (unsigned)b * SPAN);
            atomicAdd(&scn[b], 1);
        } else bv[j] = -1;
    }
    __syncthreads();
    int c = scn[tid];
    for (int off = 1; off < 256; off <<= 1) {
        int t = (tid >= off) ? scn[tid - off] : 0;
        __syncthreads();
        scn[tid] += t;
        __syncthreads();
    }
    int ex = scn[tid] - c;
    lbase[tid] = ex;
    run[tid] = ex;
    if (c > 0) gbase[tid] = atomicAdd(&gcur[tid], c);
    __syncthreads();

    #pragma unroll
    for (int j = 0; j < BK_PER; ++j) {
        if (bv[j] >= 0) {
            int p = atomicAdd(&run[bv[j]], 1);
            stage[p] = pv[j];
            bkt[p] = (unsigned char)bv[j];
        }
    }
    __syncthreads();

    int total = min(BK_TILE, E - base);
    for (int i = tid; i < total; i += 256) {
        int bb = bkt[i];
        pairs[gbase[bb] + (i - lbase[bb])] = stage[i];
    }
}

// Phase B: one block per bucket. Local node hist -> scan -> row_ptr/dinv/col,
// then fused prescale Y = half(dinv ⊙ x), written COLUMN-CHUNKED:
// slab c holds cols [c*16,(c+1)*16) as [N][16] halves.
__global__ __launch_bounds__(256) void k_finish(const unsigned* __restrict__ pairs,
                                                const int* __restrict__ bucketBase,
                                                int* __restrict__ row_ptr,
                                                float* __restrict__ dinv,
                                                int* __restrict__ col,
                                                const float* __restrict__ x,
                                                __half* __restrict__ Y, int N) {
    __shared__ int lh[512];
    __shared__ int sa[512];
    __shared__ int sb[512];
    __shared__ int lcur[SPAN];
    const int tid = threadIdx.x;
    const int b = blockIdx.x;
    const int lo = b * SPAN;
    const int hi = min(lo + SPAN, N);
    const int nn = hi - lo;
    const int p0 = bucketBase[b];
    const int p1 = bucketBase[b + 1];

    for (int i = tid; i < 512; i += 256) lh[i] = 0;
    __syncthreads();
    for (int e = p0 + tid; e < p1; e += 256)
        atomicAdd(&lh[pairs[e] & 511u], 1);
    __syncthreads();
    int* cur = sa;
    int* nxt = sb;
    for (int i = tid; i < 512; i += 256) sa[i] = lh[i];
    __syncthreads();
    for (int off = 1; off < 512; off <<= 1) {
        for (int i = tid; i < 512; i += 256)
            nxt[i] = cur[i] + ((i >= off) ? cur[i - off] : 0);
        __syncthreads();
        int* t = cur; cur = nxt; nxt = t;
    }
    for (int i = tid; i < nn; i += 256) {
        int cnt  = lh[i];
        int base = p0 + cur[i] - cnt;
        row_ptr[lo + i] = base;
        lcur[i] = base;
        dinv[lo + i] = rsqrtf(1.0f + (float)cnt);   // +1 self-loop
    }
    if (b == NB - 1 && tid == 0) row_ptr[N] = p1;
    __syncthreads();
    for (int e = p0 + tid; e < p1; e += 256) {
        unsigned pr = pairs[e];
        int pos = atomicAdd(&lcur[pr & 511u], 1);
        col[pos] = (int)(pr >> 9);
    }
    // fused prescale (chunked): seg handles cols [seg*8, seg*8+8) ->
    // slab seg>>1, within-row offset (seg&1)*8.
    const int seg = tid & 7;
    for (int rr = tid >> 3; rr < nn; rr += 32) {
        float di = rsqrtf(1.0f + (float)lh[rr]);
        long row = lo + rr;
        float4 a = ((const float4*)x)[row * 16 + seg * 2];
        float4 c = ((const float4*)x)[row * 16 + seg * 2 + 1];
        float f[8] = {a.x * di, a.y * di, a.z * di, a.w * di,
                      c.x * di, c.y * di, c.z * di, c.w * di};
        __half* dst = Y + ((size_t)(seg >> 1) * N + row) * 16 + (seg & 1) * 8;
        *(float4*)dst = f8_to_h8(f);
    }
}

// ---------------- chunked aggregation over one 16-col slab ----------------
// FINAL=false: Xf[g][c*16 + p*8 ..] = half( dinv[g] * (slab[g] + sum slab[s]) )
// FINAL=true : out[g][c*16+ ..]     = dinv[g] * (...) + bias[c*16+..]  (fp32)
// 128 nodes/block, 2 lanes/node (p = which 16B half of the 32B slab row).
template<bool FINAL>
__global__ __launch_bounds__(256) void k_aggc(const int* __restrict__ row_ptr,
                                              const int* __restrict__ col,
                                              const float* __restrict__ dinv,
                                              const __half* __restrict__ slab, // [N][16]
                                              const float* __restrict__ bias,  // [64] (FINAL)
                                              void* __restrict__ outv,
                                              int c, int n) {
    int g = blockIdx.x * 128 + (threadIdx.x >> 1);
    if (g >= n) return;
    int p = threadIdx.x & 1;
    const float4* P2 = (const float4*)slab;     // node*2 + p
    float accA[8] = {}, accB[8] = {};
    h8_add(P2[(long)g * 2 + p], accA);          // self term (pre-scaled payload)
    gatherc(P2, col, row_ptr[g], row_ptr[g + 1], p, accA, accB);

    float di = dinv[g];
    float r[8];
    #pragma unroll
    for (int i = 0; i < 8; ++i) r[i] = (accA[i] + accB[i]) * di;
    if (FINAL) {
        const float* bc = bias + c * 16 + p * 8;
        #pragma unroll
        for (int i = 0; i < 8; ++i) r[i] += bc[i];
        float* o = (float*)outv + (long)g * 64 + c * 16 + p * 8;
        *(float4*)o       = make_float4(r[0], r[1], r[2], r[3]);
        *(float4*)(o + 4) = make_float4(r[4], r[5], r[6], r[7]);
    } else {
        __half* o = (__half*)outv + (long)g * 64 + c * 16 + p * 8;
        *(float4*)o = f8_to_h8(r);
    }
}

// ---------------- MFMA MLP: Xch = half(dinv ⊙ relu(Xf W1 + b1) W2) ----------------
// Input Xf full-row [N][64]h; output CHUNKED Xch (4 slabs [N][16]h) for agg2.
// 64-row tile, 256 threads, 4 waves (R11-proven structure).
__global__ __launch_bounds__(256) void k_mlp_c(const _Float16* __restrict__ G,   // [N,64]
                                               const _Float16* __restrict__ W1t, // [128,64]
                                               const float* __restrict__ b1,     // [128]
                                               const _Float16* __restrict__ W2t, // [64,128]
                                               const float* __restrict__ dscale,
                                               _Float16* __restrict__ Xch,       // 4x[N][16]
                                               int M) {
    __shared__ __align__(16) _Float16 Hs[64 * 136];  // 17.4 KB
    __shared__ __align__(16) _Float16 Os[64 * 72];   // 9.2 KB
    const int tid = threadIdx.x;
    const int row0 = blockIdx.x * 64;
    const int wv = tid >> 6;
    const int l64 = tid & 63;
    const int lr = l64 & 15;
    const int lg = l64 >> 4;

    const int arow = row0 + wv * 16 + lr;
    f16x8 a0 = {}, a1 = {};
    if (arow < M) {
        a0 = *(const f16x8*)(G + (long)arow * 64 + lg * 8);
        a1 = *(const f16x8*)(G + (long)arow * 64 + 32 + lg * 8);
    }
    const _Float16* wb1 = W1t + lr * 64 + lg * 8;
    f32x4 acc[8];
    #pragma unroll
    for (int nt = 0; nt < 8; ++nt) acc[nt] = (f32x4){0.f, 0.f, 0.f, 0.f};
    #pragma unroll
    for (int nt = 0; nt < 8; ++nt) {
        f16x8 b0 = *(const f16x8*)(wb1 + nt * 1024);
        f16x8 bK = *(const f16x8*)(wb1 + nt * 1024 + 32);
        acc[nt] = __builtin_amdgcn_mfma_f32_16x16x32_f16(a0, b0, acc[nt], 0, 0, 0);
        acc[nt] = __builtin_amdgcn_mfma_f32_16x16x32_f16(a1, bK, acc[nt], 0, 0, 0);
    }
    #pragma unroll
    for (int nt = 0; nt < 8; ++nt) {
        float bv = b1[nt * 16 + lr];
        #pragma unroll
        for (int r = 0; r < 4; ++r) {
            float h = fmaxf(acc[nt][r] + bv, 0.f);
            Hs[(wv * 16 + lg * 4 + r) * 136 + nt * 16 + lr] = (_Float16)h;
        }
    }
    __syncthreads();

    const _Float16* wb2 = W2t + lr * 128 + lg * 8;
    const _Float16* hrow = &Hs[(wv * 16 + lr) * 136 + lg * 8];
    f32x4 acc2[4];
    #pragma unroll
    for (int nt = 0; nt < 4; ++nt) acc2[nt] = (f32x4){0.f, 0.f, 0.f, 0.f};
    #pragma unroll
    for (int kk = 0; kk < 4; ++kk) {
        f16x8 a = *(const f16x8*)(hrow + kk * 32);
        #pragma unroll
        for (int nt = 0; nt < 4; ++nt) {
            f16x8 b = *(const f16x8*)(wb2 + nt * 2048 + kk * 32);
            acc2[nt] = __builtin_amdgcn_mfma_f32_16x16x32_f16(a, b, acc2[nt], 0, 0, 0);
        }
    }
    float sc[4];
    #pragma unroll
    for (int r = 0; r < 4; ++r) {
        int gr = row0 + wv * 16 + lg * 4 + r;
        sc[r] = (gr < M) ? dscale[gr] : 0.f;
    }
    #pragma unroll
    for (int nt = 0; nt < 4; ++nt) {
        #pragma unroll
        for (int r = 0; r < 4; ++r)
            Os[(wv * 16 + lg * 4 + r) * 72 + nt * 16 + lr] = (_Float16)(acc2[nt][r] * sc[r]);
    }
    __syncthreads();

    // chunked store: thread t -> row t>>2, cols c0=(t&3)*16 -> slab c0/16.
    {
        int r = tid >> 2, c0 = (tid & 3) * 16;
        int gr = row0 + r;
        if (gr < M) {
            f16x8 v0 = *(const f16x8*)&Os[r * 72 + c0];
            f16x8 v1 = *(const f16x8*)&Os[r * 72 + c0 + 8];
            _Float16* dst = Xch + ((size_t)(c0 >> 4) * M + gr) * 16;
            *(f16x8*)dst = v0;
            *(f16x8*)(dst + 8) = v1;
        }
    }
}

// ---------------- fallback path (float, atomic scatter; only if ws too small) ----------------
__global__ __launch_bounds__(256) void k_init_deg(float* deg, int n) {
    int i = blockIdx.x * 256 + threadIdx.x;
    if (i < n) deg[i] = 1.0f;
}
__global__ __launch_bounds__(256) void k_count_deg(const int* __restrict__ ei, float* deg, int E) {
    int e = blockIdx.x * 256 + threadIdx.x;
    if (e < E) atomAddF(&deg[ei[E + e]], 1.0f);
}
__global__ __launch_bounds__(256) void k_rsqrt(float* deg, int n) {
    int i = blockIdx.x * 256 + threadIdx.x;
    if (i < n) deg[i] = rsqrtf(deg[i]);
}
template<bool BIAS>
__global__ __launch_bounds__(256) void k_self(const float* __restrict__ src,
                                              const float* __restrict__ dinv,
                                              const float* __restrict__ b,
                                              float* __restrict__ out, int n) {
    int g = blockIdx.x * 256 + threadIdx.x;
    int i = g >> 4, c = g & 15;
    if (i >= n) return;
    float di = dinv[i];
    float s = di * di;
    float4 v = *(const float4*)&src[(long)i * DIM + c * 4];
    float4 r = make_float4(v.x * s, v.y * s, v.z * s, v.w * s);
    if (BIAS) {
        float4 bv = *(const float4*)&b[c * 4];
        r.x += bv.x; r.y += bv.y; r.z += bv.z; r.w += bv.w;
    }
    *(float4*)&out[(long)i * DIM + c * 4] = r;
}
__global__ __launch_bounds__(256) void k_edge_agg(const int* __restrict__ ei,
                                                  const float* __restrict__ dinv,
                                                  const float* __restrict__ h,
                                                  float* __restrict__ out, int E) {
    int t = threadIdx.x;
    int e = blockIdx.x * 16 + (t >> 4);
    if (e >= E) return;
    int lane = t & 15;
    int s = ei[e];
    int d = ei[E + e];
    float norm = dinv[s] * dinv[d];
    float4 hv = *(const float4*)&h[(long)s * DIM + lane * 4];
    float* o = &out[(long)d * DIM + lane * 4];
    atomAddF(o + 0, hv.x * norm);
    atomAddF(o + 1, hv.y * norm);
    atomAddF(o + 2, hv.z * norm);
    atomAddF(o + 3, hv.w * norm);
}
// float-I/O MLP for the fallback path
__global__ __launch_bounds__(256) void k_mlp_f(const float* __restrict__ G,
                                               const float* __restrict__ W1,
                                               const float* __restrict__ b1,
                                               const float* __restrict__ W2,
                                               float* __restrict__ T, int M) {
    __shared__ float Ws[64 * 128];
    __shared__ float HA[64 * 132];
    const int tid = threadIdx.x;
    const int row0 = blockIdx.x * 64;
    const int ty = tid >> 4;
    const int tx = tid & 15;
    #pragma unroll
    for (int l = 0; l < 4; ++l) {
        int idx = l * 256 + tid;
        int r = idx >> 4, cv = idx & 15;
        int gr = row0 + r;
        float4 v = make_float4(0.f, 0.f, 0.f, 0.f);
        if (gr < M) v = *(const float4*)&G[(long)gr * DIM + cv * 4];
        *(float4*)&HA[r * 68 + cv * 4] = v;
    }
    #pragma unroll
    for (int l = 0; l < 8; ++l) {
        int idx = (l * 256 + tid) * 4;
        *(float4*)&Ws[idx] = *(const float4*)&W1[idx];
    }
    __syncthreads();
    float4 accA[4], accB[4];
    #pragma unroll
    for (int i = 0; i < 4; ++i) {
        accA[i] = make_float4(0.f, 0.f, 0.f, 0.f);
        accB[i] = make_float4(0.f, 0.f, 0.f, 0.f);
    }
    for (int k4 = 0; k4 < 64; k4 += 4) {
        float4 a[4];
        #pragma unroll
        for (int i = 0; i < 4; ++i) a[i] = *(const float4*)&HA[(ty * 4 + i) * 68 + k4];
        #pragma unroll
        for (int kk = 0; kk < 4; ++kk) {
            const float* wr = &Ws[(k4 + kk) * 128 + tx * 8];
            float4 wA = *(const float4*)wr;
            float4 wB = *(const float4*)(wr + 4);
            #pragma unroll
            for (int i = 0; i < 4; ++i) {
                float ak = (&a[i].x)[kk];
                accA[i].x += ak * wA.x; accA[i].y += ak * wA.y;
                accA[i].z += ak * wA.z; accA[i].w += ak * wA.w;
                accB[i].x += ak * wB.x; accB[i].y += ak * wB.y;
                accB[i].z += ak * wB.z; accB[i].w += ak * wB.w;
            }
        }
    }
    __syncthreads();
    {
        float4 bA = *(const float4*)&b1[tx * 8];
        float4 bB = *(const float4*)&b1[tx * 8 + 4];
        #pragma unroll
        for (int i = 0; i < 4; ++i) {
            float4 hA = make_float4(fmaxf(accA[i].x + bA.x, 0.f), fmaxf(accA[i].y + bA.y, 0.f),
                                    fmaxf(accA[i].z + bA.z, 0.f), fmaxf(accA[i].w + bA.w, 0.f));
            float4 hB = make_float4(fmaxf(accB[i].x + bB.x, 0.f), fmaxf(accB[i].y + bB.y, 0.f),
                                    fmaxf(accB[i].z + bB.z, 0.f), fmaxf(accB[i].w + bB.w, 0.f));
            *(float4*)&HA[(ty * 4 + i) * 132 + tx * 8 + 0] = hA;
            *(float4*)&HA[(ty * 4 + i) * 132 + tx * 8 + 4] = hB;
        }
    }
    #pragma unroll
    for (int l = 0; l < 8; ++l) {
        int idx = (l * 256 + tid) * 4;
        *(float4*)&Ws[idx] = *(const float4*)&W2[idx];
    }
    __syncthreads();
    float4 o[4];
    #pragma unroll
    for (int i = 0; i < 4; ++i) o[i] = make_float4(0.f, 0.f, 0.f, 0.f);
    for (int k4 = 0; k4 < 128; k4 += 4) {
        float4 a[4];
        #pragma unroll
        for (int i = 0; i < 4; ++i) a[i] = *(const float4*)&HA[(ty * 4 + i) * 132 + k4];
        #pragma unroll
        for (int kk = 0; kk < 4; ++kk) {
            float4 w = *(const float4*)&Ws[(k4 + kk) * 64 + tx * 4];
            #pragma unroll
            for (int i = 0; i < 4; ++i) {
                float ak = (&a[i].x)[kk];
                o[i].x += ak * w.x; o[i].y += ak * w.y;
                o[i].z += ak * w.z; o[i].w += ak * w.w;
            }
        }
    }
    #pragma unroll
    for (int i = 0; i < 4; ++i) {
        int gr = row0 + ty * 4 + i;
        if (gr < M) *(float4*)&T[(long)gr * DIM + tx * 4] = o[i];
    }
}

extern "C" void kernel_launch(void* const* d_in, const int* in_sizes, int n_in,
                              void* d_out, int out_size, void* d_ws, size_t ws_size,
                              hipStream_t stream) {
    const float* x  = (const float*)d_in[0];
    const int*   ei = (const int*)d_in[1];   // [2,E] int32
    const float* W1 = (const float*)d_in[2];
    const float* b1 = (const float*)d_in[3];
    const float* W2 = (const float*)d_in[4];
    const float* b2 = (const float*)d_in[5];
    float* out = (float*)d_out;

    const int N = in_sizes[0] / DIM;   // 100000
    const int E = in_sizes[1] / 2;     // 1600000

    const int gn   = (N + 255) / 256;
    const int ge   = (E + 255) / 256;
    const int gac  = (N + 127) / 128;  // chunked agg: 128 nodes/block
    const int gmlp = (N + 63) / 64;
    const int gbk  = (E + BK_TILE - 1) / BK_TILE;

    // ws layout (256B-aligned bump).
    size_t off = 0;
    auto bump = [&](size_t bytes) { size_t o = off; off = (off + bytes + 255) & ~(size_t)255; return o; };
    size_t o_dinv   = bump((size_t)N * 4);
    size_t o_rowptr = bump((size_t)(N + 1) * 4);
    size_t o_bcnt   = bump(NB * 4);
    size_t o_bbase  = bump((NB + 1) * 4);
    size_t o_gcur   = bump(NB * 4);
    size_t o_col    = bump((size_t)E * 4);
    size_t o_Y      = bump((size_t)N * DIM * 2);   // chunked prescaled x (4 slabs)
    size_t o_Xf     = bump((size_t)N * DIM * 2);   // full-row agg1 out / MLP in
    size_t o_Xc     = bump((size_t)N * DIM * 2);   // chunked MLP out (agg2 payload)
    size_t o_pairs  = bump((size_t)E * 4);         // packed edges (dead after k_finish)
    size_t o_W1t    = bump(128 * 64 * 2);          // half W1^T
    size_t o_W2t    = bump(64 * 128 * 2);          // half W2^T
    size_t need_csr = off;                         // ~52 MB

    char* ws = (char*)d_ws;

    if (ws_size >= need_csr) {
        float*    dinv   = (float*)(ws + o_dinv);
        int*      rowptr = (int*)(ws + o_rowptr);
        int*      bcnt   = (int*)(ws + o_bcnt);
        int*      bbase  = (int*)(ws + o_bbase);
        int*      gcur   = (int*)(ws + o_gcur);
        int*      col    = (int*)(ws + o_col);
        __half*   Y      = (__half*)(ws + o_Y);
        __half*   Xf     = (__half*)(ws + o_Xf);
        _Float16* Xc     = (_Float16*)(ws + o_Xc);
        unsigned* pairs  = (unsigned*)(ws + o_pairs);
        _Float16* W1t    = (_Float16*)(ws + o_W1t);
        _Float16* W2t    = (_Float16*)(ws + o_W2t);

        k_wconv<<<64, 256, 0, stream>>>(W1, W2, W1t, W2t, bcnt);
        k_hist256<<<gbk, 256, 0, stream>>>(ei, bcnt, E);
        k_scan_b<<<1, 256, 0, stream>>>(bcnt, bbase, gcur);
        k_bucket<<<gbk, 256, 0, stream>>>(ei, gcur, pairs, E);
        // CSR finalize + fused chunked prescale: Y slabs = half(dinv ⊙ x)
        k_finish<<<NB, 256, 0, stream>>>(pairs, bbase, rowptr, dinv, col, x, Y, N);
        // agg1 chunked: Xf full-row = half(Ahat x), one 3.2MB slab per pass
        for (int c = 0; c < 4; ++c)
            k_aggc<false><<<gac, 256, 0, stream>>>(
                rowptr, col, dinv, (const __half*)(Y + (size_t)c * N * 16),
                nullptr, (void*)Xf, c, N);
        // MLP: Xc (chunked) = half( dinv ⊙ relu(Xf W1 + b1) W2 )
        k_mlp_c<<<gmlp, 256, 0, stream>>>((const _Float16*)Xf, W1t, b1, W2t, dinv,
                                          Xc, N);
        // agg2 chunked: out = dinv[d]*(Xc[d] + sum Xc[s]) + b2
        for (int c = 0; c < 4; ++c)
            k_aggc<true><<<gac, 256, 0, stream>>>(
                rowptr, col, dinv, (const __half*)(Xc + (size_t)c * N * 16),
                b2, (void*)out, c, N);
    } else {
        // -------- fallback (float atomic scatter) --------
        float* dinv = (float*)ws;
        float* buf  = (float*)(ws + 512 * 1024);
        int grow16 = ((long)N * 16 + 255) / 256;
        int gedge = (E + 15) / 16;

        k_init_deg<<<gn, 256, 0, stream>>>(dinv, N);
        k_count_deg<<<ge, 256, 0, stream>>>(ei, dinv, E);
        k_rsqrt<<<gn, 256, 0, stream>>>(dinv, N);

        k_self<false><<<grow16, 256, 0, stream>>>(x, dinv, nullptr, buf, N);
        k_edge_agg<<<gedge, 256, 0, stream>>>(ei, dinv, x, buf, E);
        k_mlp_f<<<gmlp, 256, 0, stream>>>(buf, W1, b1, W2, buf, N);
        k_self<true><<<grow16, 256, 0, stream>>>(buf, dinv, b2, out, N);
        k_edge_agg<<<gedge, 256, 0, stream>>>(ei, dinv, buf, out, E);
    }
}

// Round 8
// 231.765 us; speedup vs baseline: 5.3069x; 1.3416x over previous
//
#include <hip/hip_runtime.h>
#include <hip/hip_fp16.h>

// GCN 2-layer: out = Ahat( relu( Ahat(x) W1 + b1 ) W2 ) + b2, Ahat = D^-1/2 (A+I) D^-1/2.
// N=100000, E=1.6M, dims 64->128->64.
//
// R16 post-mortem: column-chunking regressed (310.9us; ~30us/chunk >= 15us
// falsifier). Root cause of the whole R13-R16 arc: FETCH 83.5MB IS the
// per-XCD compulsory floor (per XCD ~88K unique rows = 11.3MB x 8 = 90MB).
// Locality schemes cannot reduce it; the gather is bound by L2-fill
// latency/miss-queue with fetch at its floor. fp8 payload (halves bytes+misses)
// projected error ~1e-2 vs 1.06e-2 threshold -- rejected.
// R17: revert to best-known R14 (234.5us) + ONE surgical fix: software-pipeline
// the col reload in gather1 (prefetch next 8 cols before draining the current
// window) so the dependent index fetch hides under the adds. If null, this is
// the structural floor (declare roofline).

#define DIM 64
#define NB 256          // dst-range buckets
#define SPAN 391        // ceil(100000/256); NB*SPAN >= N; SPAN < 512
#define BK_TILE 4096
#define BK_PER 16       // edges per thread in k_bucket

typedef _Float16 f16x8 __attribute__((ext_vector_type(8)));
typedef float f32x4 __attribute__((ext_vector_type(4)));

__device__ __forceinline__ void atomAddF(float* p, float v) {
    unsafeAtomicAdd(p, v);
}

// 8 halves (packed in float4) -> add into 8 fp32 accumulators
__device__ __forceinline__ void h8_add(const float4 v, float* acc) {
    const __half2* hp = (const __half2*)&v;
    #pragma unroll
    for (int i = 0; i < 4; ++i) {
        float2 t = __half22float2(hp[i]);
        acc[2 * i] += t.x;
        acc[2 * i + 1] += t.y;
    }
}
// 8 fp32 -> 8 halves packed in a float4
__device__ __forceinline__ float4 f8_to_h8(const float* f) {
    __half2 hh[4];
    hh[0] = __float22half2_rn(make_float2(f[0], f[1]));
    hh[1] = __float22half2_rn(make_float2(f[2], f[3]));
    hh[2] = __float22half2_rn(make_float2(f[4], f[5]));
    hh[3] = __float22half2_rn(make_float2(f[6], f[7]));
    return *(float4*)hh;
}

// Single-chain 8-deep CSR gather with SOFTWARE-PIPELINED col prefetch:
// next window's 8 col indices are issued BEFORE the current window's drain,
// so the dependent index fetch overlaps the h8_add chain.
__device__ __forceinline__ void gather1(const float4* __restrict__ h4,
                                        const int* __restrict__ col,
                                        int e, int e1, int lane, float* accA, float* accB) {
    if (e + 8 <= e1) {
        int c0 = col[e], c1 = col[e + 1], c2 = col[e + 2], c3 = col[e + 3];
        int c4 = col[e + 4], c5 = col[e + 5], c6 = col[e + 6], c7 = col[e + 7];
        e += 8;
        while (true) {
            float4 v0 = h4[(long)c0 * 8 + lane];
            float4 v1 = h4[(long)c1 * 8 + lane];
            float4 v2 = h4[(long)c2 * 8 + lane];
            float4 v3 = h4[(long)c3 * 8 + lane];
            float4 v4 = h4[(long)c4 * 8 + lane];
            float4 v5 = h4[(long)c5 * 8 + lane];
            float4 v6 = h4[(long)c6 * 8 + lane];
            float4 v7 = h4[(long)c7 * 8 + lane];
            bool more = (e + 8 <= e1);
            if (more) {
                c0 = col[e]; c1 = col[e + 1]; c2 = col[e + 2]; c3 = col[e + 3];
                c4 = col[e + 4]; c5 = col[e + 5]; c6 = col[e + 6]; c7 = col[e + 7];
            }
            h8_add(v0, accA); h8_add(v1, accB);
            h8_add(v2, accA); h8_add(v3, accB);
            h8_add(v4, accA); h8_add(v5, accB);
            h8_add(v6, accA); h8_add(v7, accB);
            if (!more) break;
            e += 8;
        }
    }
    for (; e + 2 <= e1; e += 2) {
        float4 v0 = h4[(long)col[e] * 8 + lane];
        float4 v1 = h4[(long)col[e + 1] * 8 + lane];
        h8_add(v0, accA); h8_add(v1, accB);
    }
    if (e < e1) h8_add(h4[(long)col[e] * 8 + lane], accA);
}

// ---------------- weight prep (+ bcnt zeroing piggyback) ----------------
// W1t[n][k] = half(W1[k][n]), W2t[n][k] = half(W2[k][n]): a lane's 8 contiguous
// k-elements of the B fragment are one 16B load.
__global__ __launch_bounds__(256) void k_wconv(const float* __restrict__ W1,
                                               const float* __restrict__ W2,
                                               _Float16* __restrict__ W1t,
                                               _Float16* __restrict__ W2t,
                                               int* __restrict__ bcnt) {
    int idx = blockIdx.x * 256 + threadIdx.x;
    if (blockIdx.x == 0) bcnt[threadIdx.x] = 0;
    if (idx < 8192) {                       // W1t: [128 n][64 k]
        int n = idx >> 6, k = idx & 63;
        W1t[idx] = (_Float16)W1[k * 128 + n];
    } else if (idx < 16384) {               // W2t: [64 n][128 k]
        int j = idx - 8192;
        int n = j >> 7, k = j & 127;
        W2t[j] = (_Float16)W2[k * 64 + n];
    }
}

// ---------------- bucket totals ----------------
__global__ __launch_bounds__(256) void k_hist256(const int* __restrict__ ei,
                                                 int* __restrict__ bucketCnt, int E) {
    __shared__ int h[NB];
    const int tid = threadIdx.x;
    h[tid] = 0;
    __syncthreads();
    const int base = blockIdx.x * BK_TILE;
    #pragma unroll
    for (int j = 0; j < BK_TILE; j += 256) {
        int e = base + j + tid;
        if (e < E) atomicAdd(&h[(unsigned)ei[E + e] / (unsigned)SPAN], 1);
    }
    __syncthreads();
    if (h[tid]) atomicAdd(&bucketCnt[tid], h[tid]);
}
__global__ __launch_bounds__(256) void k_scan_b(const int* __restrict__ bucketCnt,
                                                int* __restrict__ bucketBase,
                                                int* __restrict__ gcur) {
    __shared__ int s[NB];
    const int tid = threadIdx.x;
    int v = bucketCnt[tid];
    s[tid] = v;
    __syncthreads();
    for (int off = 1; off < NB; off <<= 1) {
        int t = (tid >= off) ? s[tid - off] : 0;
        __syncthreads();
        s[tid] += t;
        __syncthreads();
    }
    int ex = s[tid] - v;
    bucketBase[tid] = ex;
    gcur[tid] = ex;
    if (tid == NB - 1) bucketBase[NB] = s[NB - 1];
}

// Phase A: tile multisplit -> bucket-grouped packed edges ((src<<9)|local_dst).
__global__ __launch_bounds__(256) void k_bucket(const int* __restrict__ ei,
                                                int* __restrict__ gcur,
                                                unsigned* __restrict__ pairs, int E) {
    __shared__ int scn[NB];
    __shared__ int run[NB];
    __shared__ int lbase[NB];
    __shared__ int gbase[NB];
    __shared__ unsigned stage[BK_TILE];
    __shared__ unsigned char bkt[BK_TILE];
    const int tid = threadIdx.x;
    const int base = blockIdx.x * BK_TILE;

    scn[tid] = 0;
    __syncthreads();

    unsigned pv[BK_PER];
    int bv[BK_PER];
    #pragma unroll
    for (int j = 0; j < BK_PER; ++j) {
        int e = base + j * 256 + tid;
        if (e < E) {
            unsigned s = (unsigned)ei[e];
            unsigned d = (unsigned)ei[E + e];
            int b = (int)(d / (unsigned)SPAN);
            bv[j] = b;
            pv[j] = (s << 9) | (d - (unsigned)b * SPAN);
            atomicAdd(&scn[b], 1);
        } else bv[j] = -1;
    }
    __syncthreads();
    int c = scn[tid];
    for (int off = 1; off < 256; off <<= 1) {
        int t = (tid >= off) ? scn[tid - off] : 0;
        __syncthreads();
        scn[tid] += t;
        __syncthreads();
    }
    int ex = scn[tid] - c;
    lbase[tid] = ex;
    run[tid] = ex;
    if (c > 0) gbase[tid] = atomicAdd(&gcur[tid], c);
    __syncthreads();

    #pragma unroll
    for (int j = 0; j < BK_PER; ++j) {
        if (bv[j] >= 0) {
            int p = atomicAdd(&run[bv[j]], 1);
            stage[p] = pv[j];
            bkt[p] = (unsigned char)bv[j];
        }
    }
    __syncthreads();

    int total = min(BK_TILE, E - base);
    for (int i = tid; i < total; i += 256) {
        int bb = bkt[i];
        pairs[gbase[bb] + (i - lbase[bb])] = stage[i];
    }
}

// Phase B: one block per bucket. Local node hist -> scan -> row_ptr/dinv/col,
// then fused prescale Y = half(dinv ⊙ x) for this bucket's rows.
__global__ __launch_bounds__(256) void k_finish(const unsigned* __restrict__ pairs,
                                                const int* __restrict__ bucketBase,
                                                int* __restrict__ row_ptr,
                                                float* __restrict__ dinv,
                                                int* __restrict__ col,
                                                const float* __restrict__ x,
                                                __half* __restrict__ Y, int N) {
    __shared__ int lh[512];
    __shared__ int sa[512];
    __shared__ int sb[512];
    __shared__ int lcur[SPAN];
    const int tid = threadIdx.x;
    const int b = blockIdx.x;
    const int lo = b * SPAN;
    const int hi = min(lo + SPAN, N);
    const int nn = hi - lo;
    const int p0 = bucketBase[b];
    const int p1 = bucketBase[b + 1];

    for (int i = tid; i < 512; i += 256) lh[i] = 0;
    __syncthreads();
    for (int e = p0 + tid; e < p1; e += 256)
        atomicAdd(&lh[pairs[e] & 511u], 1);
    __syncthreads();
    int* cur = sa;
    int* nxt = sb;
    for (int i = tid; i < 512; i += 256) sa[i] = lh[i];
    __syncthreads();
    for (int off = 1; off < 512; off <<= 1) {
        for (int i = tid; i < 512; i += 256)
            nxt[i] = cur[i] + ((i >= off) ? cur[i - off] : 0);
        __syncthreads();
        int* t = cur; cur = nxt; nxt = t;
    }
    for (int i = tid; i < nn; i += 256) {
        int cnt  = lh[i];
        int base = p0 + cur[i] - cnt;
        row_ptr[lo + i] = base;
        lcur[i] = base;
        dinv[lo + i] = rsqrtf(1.0f + (float)cnt);   // +1 self-loop
    }
    if (b == NB - 1 && tid == 0) row_ptr[N] = p1;
    __syncthreads();
    for (int e = p0 + tid; e < p1; e += 256) {
        unsigned pr = pairs[e];
        int pos = atomicAdd(&lcur[pr & 511u], 1);
        col[pos] = (int)(pr >> 9);
    }
    // fused prescale: Y[row] = half(dinv[row] * x[row]) for rows [lo,hi).
    // lh[] still holds counts (sa/sb were the scan buffers). 8 lanes/row.
    const int seg = tid & 7;
    for (int rr = tid >> 3; rr < nn; rr += 32) {
        float di = rsqrtf(1.0f + (float)lh[rr]);
        long row = lo + rr;
        float4 a = ((const float4*)x)[row * 16 + seg * 2];
        float4 c = ((const float4*)x)[row * 16 + seg * 2 + 1];
        float f[8] = {a.x * di, a.y * di, a.z * di, a.w * di,
                      c.x * di, c.y * di, c.z * di, c.w * di};
        ((float4*)Y)[row * 8 + seg] = f8_to_h8(f);
    }
}

// ---------------- final aggregation: out = dinv[d]*(X[d]+sum X[s]) + b2 ----
// 32 nodes/block, 8 lanes/node, pipelined 8-deep gather.
__global__ __launch_bounds__(256) void k_agg_fin(const int* __restrict__ row_ptr,
                                                 const int* __restrict__ col,
                                                 const float* __restrict__ dinv,
                                                 const __half* __restrict__ ph,
                                                 const float* __restrict__ bias,
                                                 float* __restrict__ outv, int n) {
    int g = blockIdx.x * 32 + (threadIdx.x >> 3);
    if (g >= n) return;
    int lane = threadIdx.x & 7;
    const float4* h4 = (const float4*)ph;
    float accA[8] = {}, accB[8] = {};
    h8_add(h4[(long)g * 8 + lane], accA);   // self (prescaled)
    gather1(h4, col, row_ptr[g], row_ptr[g + 1], lane, accA, accB);

    float di = dinv[g];
    float r[8];
    #pragma unroll
    for (int i = 0; i < 8; ++i) r[i] = (accA[i] + accB[i]) * di;
    float4 b0 = ((const float4*)bias)[lane * 2];
    float4 b1v = ((const float4*)bias)[lane * 2 + 1];
    r[0] += b0.x; r[1] += b0.y; r[2] += b0.z; r[3] += b0.w;
    r[4] += b1v.x; r[5] += b1v.y; r[6] += b1v.z; r[7] += b1v.w;
    *(float4*)&outv[(long)g * 64 + lane * 8]     = make_float4(r[0], r[1], r[2], r[3]);
    *(float4*)&outv[(long)g * 64 + lane * 8 + 4] = make_float4(r[4], r[5], r[6], r[7]);
}

// ---------------- fused agg1 + MFMA MLP (32-row tile, 128 threads, 2 waves) ----
// X[row0..row0+32) = half( dinv ⊙ relu( (Ahat x)|tile W1 + b1 ) W2 )
// Phase 1 (agg): 16 groups x 8 lanes; group does nodes grp and grp+16
//   sequentially with the pipelined 8-deep gather; rows -> LDS Xs (stride 72).
// Phase 2 (MFMA): 2 waves, wave wv owns rows [wv*16, wv*16+16).
//   v_mfma_f32_16x16x32_f16: A row=lane&15, k=(lane>>4)*8+j; B col=lane&15, same k;
//   D col=lane&15, row=(lane>>4)*4+reg (m89/m91-verified).
// Os (output stage) aliases Xs: all Xs reads happen before the Hs barrier.
__global__ __launch_bounds__(128) void k_agg_mlp(const int* __restrict__ row_ptr,
                                                 const int* __restrict__ col,
                                                 const float* __restrict__ dinv,
                                                 const __half* __restrict__ Y,
                                                 const _Float16* __restrict__ W1t, // [128,64]
                                                 const float* __restrict__ b1,     // [128]
                                                 const _Float16* __restrict__ W2t, // [64,128]
                                                 _Float16* __restrict__ X,         // [N,64]
                                                 int M) {
    __shared__ __align__(16) _Float16 Xs[32 * 72];   // 4.6 KB (agg A-tile / out stage)
    __shared__ __align__(16) _Float16 Hs[32 * 136];  // 8.7 KB
    const int tid = threadIdx.x;
    const int row0 = blockIdx.x * 32;
    const int grp = tid >> 3;
    const int lane = tid & 7;
    const float4* h4 = (const float4*)Y;

    // ---- phase 1: aggregate nodes grp and grp+16 (sequential, 8-deep window) ----
    #pragma unroll
    for (int hh = 0; hh < 2; ++hh) {
        const int lrow = grp + hh * 16;
        const int g = row0 + lrow;
        float r[8] = {};
        if (g < M) {
            float accA[8] = {}, accB[8] = {};
            h8_add(h4[(long)g * 8 + lane], accA);   // self (prescaled)
            gather1(h4, col, row_ptr[g], row_ptr[g + 1], lane, accA, accB);
            float di = dinv[g];
            #pragma unroll
            for (int i = 0; i < 8; ++i) r[i] = (accA[i] + accB[i]) * di;
        }
        *(float4*)&Xs[lrow * 72 + lane * 8] = f8_to_h8(r);
    }
    __syncthreads();

    // ---- phase 2: MFMA MLP on the 32-row LDS tile ----
    const int wv = tid >> 6;            // 0..1
    const int l64 = tid & 63;
    const int lr = l64 & 15;
    const int lg = l64 >> 4;

    f16x8 a0 = *(const f16x8*)&Xs[(wv * 16 + lr) * 72 + lg * 8];
    f16x8 a1 = *(const f16x8*)&Xs[(wv * 16 + lr) * 72 + 32 + lg * 8];
    const _Float16* wb1 = W1t + lr * 64 + lg * 8;
    f32x4 acc[8];
    #pragma unroll
    for (int nt = 0; nt < 8; ++nt) acc[nt] = (f32x4){0.f, 0.f, 0.f, 0.f};
    #pragma unroll
    for (int nt = 0; nt < 8; ++nt) {
        f16x8 b0 = *(const f16x8*)(wb1 + nt * 1024);
        f16x8 bK = *(const f16x8*)(wb1 + nt * 1024 + 32);
        acc[nt] = __builtin_amdgcn_mfma_f32_16x16x32_f16(a0, b0, acc[nt], 0, 0, 0);
        acc[nt] = __builtin_amdgcn_mfma_f32_16x16x32_f16(a1, bK, acc[nt], 0, 0, 0);
    }
    // bias + relu -> Hs
    #pragma unroll
    for (int nt = 0; nt < 8; ++nt) {
        float bv = b1[nt * 16 + lr];
        #pragma unroll
        for (int r = 0; r < 4; ++r) {
            float h = fmaxf(acc[nt][r] + bv, 0.f);
            Hs[(wv * 16 + lg * 4 + r) * 136 + nt * 16 + lr] = (_Float16)h;
        }
    }
    __syncthreads();

    // GEMM2: K=128 in 4 steps of 32
    const _Float16* wb2 = W2t + lr * 128 + lg * 8;
    const _Float16* hrow = &Hs[(wv * 16 + lr) * 136 + lg * 8];
    f32x4 acc2[4];
    #pragma unroll
    for (int nt = 0; nt < 4; ++nt) acc2[nt] = (f32x4){0.f, 0.f, 0.f, 0.f};
    #pragma unroll
    for (int kk = 0; kk < 4; ++kk) {
        f16x8 a = *(const f16x8*)(hrow + kk * 32);
        #pragma unroll
        for (int nt = 0; nt < 4; ++nt) {
            f16x8 b = *(const f16x8*)(wb2 + nt * 2048 + kk * 32);
            acc2[nt] = __builtin_amdgcn_mfma_f32_16x16x32_f16(a, b, acc2[nt], 0, 0, 0);
        }
    }
    // scale by dinv, stage to Os (= Xs alias; Xs reads all completed pre-barrier)
    _Float16* Os = Xs;
    float sc[4];
    #pragma unroll
    for (int r = 0; r < 4; ++r) {
        int gr = row0 + wv * 16 + lg * 4 + r;
        sc[r] = (gr < M) ? dinv[gr] : 0.f;
    }
    #pragma unroll
    for (int nt = 0; nt < 4; ++nt) {
        #pragma unroll
        for (int r = 0; r < 4; ++r)
            Os[(wv * 16 + lg * 4 + r) * 72 + nt * 16 + lr] = (_Float16)(acc2[nt][r] * sc[r]);
    }
    __syncthreads();

    // coalesced store: thread t -> row t>>2, 16 halves at col (t&3)*16
    {
        int r = tid >> 2, c0 = (tid & 3) * 16;
        int gr = row0 + r;
        if (gr < M) {
            f16x8 v0 = *(const f16x8*)&Os[r * 72 + c0];
            f16x8 v1 = *(const f16x8*)&Os[r * 72 + c0 + 8];
            *(f16x8*)(X + (long)gr * 64 + c0) = v0;
            *(f16x8*)(X + (long)gr * 64 + c0 + 8) = v1;
        }
    }
}

// ---------------- fallback path (float, atomic scatter; only if ws too small) ----------------
__global__ __launch_bounds__(256) void k_init_deg(float* deg, int n) {
    int i = blockIdx.x * 256 + threadIdx.x;
    if (i < n) deg[i] = 1.0f;
}
__global__ __launch_bounds__(256) void k_count_deg(const int* __restrict__ ei, float* deg, int E) {
    int e = blockIdx.x * 256 + threadIdx.x;
    if (e < E) atomAddF(&deg[ei[E + e]], 1.0f);
}
__global__ __launch_bounds__(256) void k_rsqrt(float* deg, int n) {
    int i = blockIdx.x * 256 + threadIdx.x;
    if (i < n) deg[i] = rsqrtf(deg[i]);
}
template<bool BIAS>
__global__ __launch_bounds__(256) void k_self(const float* __restrict__ src,
                                              const float* __restrict__ dinv,
                                              const float* __restrict__ b,
                                              float* __restrict__ out, int n) {
    int g = blockIdx.x * 256 + threadIdx.x;
    int i = g >> 4, c = g & 15;
    if (i >= n) return;
    float di = dinv[i];
    float s = di * di;
    float4 v = *(const float4*)&src[(long)i * DIM + c * 4];
    float4 r = make_float4(v.x * s, v.y * s, v.z * s, v.w * s);
    if (BIAS) {
        float4 bv = *(const float4*)&b[c * 4];
        r.x += bv.x; r.y += bv.y; r.z += bv.z; r.w += bv.w;
    }
    *(float4*)&out[(long)i * DIM + c * 4] = r;
}
__global__ __launch_bounds__(256) void k_edge_agg(const int* __restrict__ ei,
                                                  const float* __restrict__ dinv,
                                                  const float* __restrict__ h,
                                                  float* __restrict__ out, int E) {
    int t = threadIdx.x;
    int e = blockIdx.x * 16 + (t >> 4);
    if (e >= E) return;
    int lane = t & 15;
    int s = ei[e];
    int d = ei[E + e];
    float norm = dinv[s] * dinv[d];
    float4 hv = *(const float4*)&h[(long)s * DIM + lane * 4];
    float* o = &out[(long)d * DIM + lane * 4];
    atomAddF(o + 0, hv.x * norm);
    atomAddF(o + 1, hv.y * norm);
    atomAddF(o + 2, hv.z * norm);
    atomAddF(o + 3, hv.w * norm);
}
// float-I/O MLP for the fallback path
__global__ __launch_bounds__(256) void k_mlp_f(const float* __restrict__ G,
                                               const float* __restrict__ W1,
                                               const float* __restrict__ b1,
                                               const float* __restrict__ W2,
                                               float* __restrict__ T, int M) {
    __shared__ float Ws[64 * 128];
    __shared__ float HA[64 * 132];
    const int tid = threadIdx.x;
    const int row0 = blockIdx.x * 64;
    const int ty = tid >> 4;
    const int tx = tid & 15;
    #pragma unroll
    for (int l = 0; l < 4; ++l) {
        int idx = l * 256 + tid;
        int r = idx >> 4, cv = idx & 15;
        int gr = row0 + r;
        float4 v = make_float4(0.f, 0.f, 0.f, 0.f);
        if (gr < M) v = *(const float4*)&G[(long)gr * DIM + cv * 4];
        *(float4*)&HA[r * 68 + cv * 4] = v;
    }
    #pragma unroll
    for (int l = 0; l < 8; ++l) {
        int idx = (l * 256 + tid) * 4;
        *(float4*)&Ws[idx] = *(const float4*)&W1[idx];
    }
    __syncthreads();
    float4 accA[4], accB[4];
    #pragma unroll
    for (int i = 0; i < 4; ++i) {
        accA[i] = make_float4(0.f, 0.f, 0.f, 0.f);
        accB[i] = make_float4(0.f, 0.f, 0.f, 0.f);
    }
    for (int k4 = 0; k4 < 64; k4 += 4) {
        float4 a[4];
        #pragma unroll
        for (int i = 0; i < 4; ++i) a[i] = *(const float4*)&HA[(ty * 4 + i) * 68 + k4];
        #pragma unroll
        for (int kk = 0; kk < 4; ++kk) {
            const float* wr = &Ws[(k4 + kk) * 128 + tx * 8];
            float4 wA = *(const float4*)wr;
            float4 wB = *(const float4*)(wr + 4);
            #pragma unroll
            for (int i = 0; i < 4; ++i) {
                float ak = (&a[i].x)[kk];
                accA[i].x += ak * wA.x; accA[i].y += ak * wA.y;
                accA[i].z += ak * wA.z; accA[i].w += ak * wA.w;
                accB[i].x += ak * wB.x; accB[i].y += ak * wB.y;
                accB[i].z += ak * wB.z; accB[i].w += ak * wB.w;
            }
        }
    }
    __syncthreads();
    {
        float4 bA = *(const float4*)&b1[tx * 8];
        float4 bB = *(const float4*)&b1[tx * 8 + 4];
        #pragma unroll
        for (int i = 0; i < 4; ++i) {
            float4 hA = make_float4(fmaxf(accA[i].x + bA.x, 0.f), fmaxf(accA[i].y + bA.y, 0.f),
                                    fmaxf(accA[i].z + bA.z, 0.f), fmaxf(accA[i].w + bA.w, 0.f));
            float4 hB = make_float4(fmaxf(accB[i].x + bB.x, 0.f), fmaxf(accB[i].y + bB.y, 0.f),
                                    fmaxf(accB[i].z + bB.z, 0.f), fmaxf(accB[i].w + bB.w, 0.f));
            *(float4*)&HA[(ty * 4 + i) * 132 + tx * 8 + 0] = hA;
            *(float4*)&HA[(ty * 4 + i) * 132 + tx * 8 + 4] = hB;
        }
    }
    #pragma unroll
    for (int l = 0; l < 8; ++l) {
        int idx = (l * 256 + tid) * 4;
        *(float4*)&Ws[idx] = *(const float4*)&W2[idx];
    }
    __syncthreads();
    float4 o[4];
    #pragma unroll
    for (int i = 0; i < 4; ++i) o[i] = make_float4(0.f, 0.f, 0.f, 0.f);
    for (int k4 = 0; k4 < 128; k4 += 4) {
        float4 a[4];
        #pragma unroll
        for (int i = 0; i < 4; ++i) a[i] = *(const float4*)&HA[(ty * 4 + i) * 132 + k4];
        #pragma unroll
        for (int kk = 0; kk < 4; ++kk) {
            float4 w = *(const float4*)&Ws[(k4 + kk) * 64 + tx * 4];
            #pragma unroll
            for (int i = 0; i < 4; ++i) {
                float ak = (&a[i].x)[kk];
                o[i].x += ak * w.x; o[i].y += ak * w.y;
                o[i].z += ak * w.z; o[i].w += ak * w.w;
            }
        }
    }
    #pragma unroll
    for (int i = 0; i < 4; ++i) {
        int gr = row0 + ty * 4 + i;
        if (gr < M) *(float4*)&T[(long)gr * DIM + tx * 4] = o[i];
    }
}

extern "C" void kernel_launch(void* const* d_in, const int* in_sizes, int n_in,
                              void* d_out, int out_size, void* d_ws, size_t ws_size,
                              hipStream_t stream) {
    const float* x  = (const float*)d_in[0];
    const int*   ei = (const int*)d_in[1];   // [2,E] int32
    const float* W1 = (const float*)d_in[2];
    const float* b1 = (const float*)d_in[3];
    const float* W2 = (const float*)d_in[4];
    const float* b2 = (const float*)d_in[5];
    float* out = (float*)d_out;

    const int N = in_sizes[0] / DIM;   // 100000
    const int E = in_sizes[1] / 2;     // 1600000

    const int gn   = (N + 255) / 256;
    const int ge   = (E + 255) / 256;
    const int gagg = (N + 31) / 32;    // 32 nodes/block (both agg kernels)
    const int gmlp = (N + 63) / 64;
    const int gbk  = (E + BK_TILE - 1) / BK_TILE;

    // ws layout (256B-aligned bump). pairs does NOT alias Y (prescale fused
    // into k_finish runs concurrently with other buckets' pairs reads).
    size_t off = 0;
    auto bump = [&](size_t bytes) { size_t o = off; off = (off + bytes + 255) & ~(size_t)255; return o; };
    size_t o_dinv   = bump((size_t)N * 4);
    size_t o_rowptr = bump((size_t)(N + 1) * 4);
    size_t o_bcnt   = bump(NB * 4);
    size_t o_bbase  = bump((NB + 1) * 4);
    size_t o_gcur   = bump(NB * 4);
    size_t o_col    = bump((size_t)E * 4);
    size_t o_X      = bump((size_t)N * DIM * 2);   // half MLP out (agg2 payload)
    size_t o_Y      = bump((size_t)N * DIM * 2);   // half prescaled x (agg1 payload)
    size_t o_pairs  = bump((size_t)E * 4);         // packed edges (dead after k_finish)
    size_t o_W1t    = bump(128 * 64 * 2);          // half W1^T
    size_t o_W2t    = bump(64 * 128 * 2);          // half W2^T
    size_t need_csr = off;                         // ~39.3 MB

    char* ws = (char*)d_ws;

    if (ws_size >= need_csr) {
        float*    dinv   = (float*)(ws + o_dinv);
        int*      rowptr = (int*)(ws + o_rowptr);
        int*      bcnt   = (int*)(ws + o_bcnt);
        int*      bbase  = (int*)(ws + o_bbase);
        int*      gcur   = (int*)(ws + o_gcur);
        int*      col    = (int*)(ws + o_col);
        __half*   X      = (__half*)(ws + o_X);
        __half*   Y      = (__half*)(ws + o_Y);
        unsigned* pairs  = (unsigned*)(ws + o_pairs);
        _Float16* W1t    = (_Float16*)(ws + o_W1t);
        _Float16* W2t    = (_Float16*)(ws + o_W2t);

        k_wconv<<<64, 256, 0, stream>>>(W1, W2, W1t, W2t, bcnt);
        k_hist256<<<gbk, 256, 0, stream>>>(ei, bcnt, E);
        k_scan_b<<<1, 256, 0, stream>>>(bcnt, bbase, gcur);
        k_bucket<<<gbk, 256, 0, stream>>>(ei, gcur, pairs, E);
        // CSR finalize + fused prescale: Y = half(dinv ⊙ x)
        k_finish<<<NB, 256, 0, stream>>>(pairs, bbase, rowptr, dinv, col, x, Y, N);
        // X = half( dinv ⊙ relu( (Ahat x) W1 + b1 ) W2 )  (fused agg1 + MFMA MLP)
        k_agg_mlp<<<gagg, 128, 0, stream>>>(rowptr, col, dinv, Y, W1t, b1, W2t,
                                            (_Float16*)X, N);
        // out = dinv[d]*(X[d] + sum X[s]) + b2
        k_agg_fin<<<gagg, 256, 0, stream>>>(rowptr, col, dinv, X, b2, out, N);
    } else {
        // -------- fallback (float atomic scatter) --------
        float* dinv = (float*)ws;
        float* buf  = (float*)(ws + 512 * 1024);
        int grow16 = ((long)N * 16 + 255) / 256;
        int gedge = (E + 15) / 16;

        k_init_deg<<<gn, 256, 0, stream>>>(dinv, N);
        k_count_deg<<<ge, 256, 0, stream>>>(ei, dinv, E);
        k_rsqrt<<<gn, 256, 0, stream>>>(dinv, N);

        k_self<false><<<grow16, 256, 0, stream>>>(x, dinv, nullptr, buf, N);
        k_edge_agg<<<gedge, 256, 0, stream>>>(ei, dinv, x, buf, E);
        k_mlp_f<<<gmlp, 256, 0, stream>>>(buf, W1, b1, W2, buf, N);
        k_self<true><<<grow16, 256, 0, stream>>>(buf, dinv, b2, out, N);
        k_edge_agg<<<gedge, 256, 0, stream>>>(ei, dinv, buf, out, E);
    }
}